// Round 1
// baseline (99.111 us; speedup 1.0000x reference)
//
#include <hip/hip_runtime.h>
#include <hip/hip_fp16.h>

// ---------------------------------------------------------------------------
// MultiNadwatSpatialConv: out[b,n,c] = sum_m Kw[n,m] fea[m,c] / (sum_m Kw + eps)
//   Kw = (0.3 e1 + 0.3 e2 + 0.4 e3) * yw[m],  e3 = exp(-d2/0.04),
//   e2 = e3^4 = exp(-d2/0.01), e1 = e3^16 = exp(-d2/0.0025), d2 = |x_n - y_m|^2
// B=2, N=M=4096, C=64. f32 in/out.
// Kernels: prep (fea->f16 pre-swizzled tiles + ypack), main (MFMA), combine.
// ---------------------------------------------------------------------------

typedef _Float16 half8 __attribute__((ext_vector_type(8)));
typedef float f32x4 __attribute__((ext_vector_type(4)));

#define C3EXP (-36.067376022224085f) /* -log2(e)/0.2^2 */
#define W_E1 0.3f
#define W_E2 0.3f
#define W_E3 0.4f

// ws layout (bytes):
//   fea16  @ 0        : B*128 tiles * (64 rows * 40 halves) = 1,310,720
//   ypack  @ 1310720  : B*M float4                           =   131,072
//   num_ws @ 1441792  : S*B*N*C f32                          = S*2,097,152
//   den_ws @ after    : S*B*N f32                            = S*32,768
#define FEA16_BYTES 1310720u
#define YPACK_OFF 1310720u
#define NUM_OFF 1441792u

__device__ __forceinline__ void gl_lds16(const void* g, void* l) {
  __builtin_amdgcn_global_load_lds(
      (const __attribute__((address_space(1))) unsigned int*)g,
      (__attribute__((address_space(3))) unsigned int*)l, 16, 0, 0);
}

__global__ __launch_bounds__(256) void prep_kernel(
    const float* __restrict__ y, const float* __restrict__ y_fea,
    const float* __restrict__ y_weight, __half* __restrict__ fea16,
    float* __restrict__ ypack) {
  int t = blockIdx.x * 256 + threadIdx.x;
  if (t < 16384) {
    // one thread per (b, tile T, channel c): write one 40-half padded row
    int b = t >> 13;
    int rT = (t >> 6) & 127;
    int c = t & 63;
    alignas(16) unsigned int u[20];
    const float* src = y_fea + ((size_t)(b << 12) + (size_t)rT * 32) * 64 + c;
#pragma unroll
    for (int k = 0; k < 16; ++k) {
      float v0 = src[(2 * k) * 64];
      float v1 = src[(2 * k + 1) * 64];
      unsigned short h0 = __half_as_ushort(__float2half(v0));
      unsigned short h1 = __half_as_ushort(__float2half(v1));
      u[k] = (unsigned int)h0 | ((unsigned int)h1 << 16);
    }
    u[16] = u[17] = u[18] = u[19] = 0u;
    uint4* dst = (uint4*)((char*)fea16 + ((size_t)((b * 128 + rT) * 64 + c)) * 80);
#pragma unroll
    for (int q = 0; q < 5; ++q) dst[q] = ((uint4*)u)[q];
  } else if (t < 16384 + 8192) {
    int t2 = t - 16384; // b*4096 + m
    float4 v;
    v.x = y[t2 * 3 + 0];
    v.y = y[t2 * 3 + 1];
    v.z = y[t2 * 3 + 2];
    v.w = y_weight[t2];
    ((float4*)ypack)[t2] = v;
  }
}

__global__ __launch_bounds__(256, 2) void main_kernel(
    const float* __restrict__ x, const __half* __restrict__ fea16,
    const float* __restrict__ ypack, float* __restrict__ num_ws,
    float* __restrict__ den_ws, int NT) {
  const int s = blockIdx.x;   // m-split index
  const int nb = blockIdx.y;  // n-block (128 rows each)
  const int b = blockIdx.z;   // batch
  const int tid = threadIdx.x;
  const int wid = tid >> 6, lane = tid & 63;
  const int g = lane >> 4, c0 = lane & 15;

  // fea tile: [c=64][40 halves] rows (80 B stride, 16B aligned, 2-way banks)
  __shared__ __half lds_fea[2][2560];
  // ypack: 4 copies (one per 16-lane group) of 32 float4, 132-float stride
  __shared__ float lds_y[2][4][132];

  const int n_base = nb * 128 + wid * 32;
  const float* xb = x + (size_t)b * 4096 * 3;
  const int n0 = n_base + c0;
  const float x00 = xb[n0 * 3 + 0], x01 = xb[n0 * 3 + 1], x02 = xb[n0 * 3 + 2];
  const float x10 = xb[(n0 + 16) * 3 + 0], x11 = xb[(n0 + 16) * 3 + 1],
              x12 = xb[(n0 + 16) * 3 + 2];

  const int t0 = s * NT; // first m-tile (32 m each) for this block

  f32x4 acc[2][4];
#pragma unroll
  for (int h = 0; h < 2; ++h)
#pragma unroll
    for (int ct = 0; ct < 4; ++ct) acc[h][ct] = (f32x4){0.f, 0.f, 0.f, 0.f};
  float den0 = 0.f, den1 = 0.f;

#define STAGE(IT, BUF)                                                        \
  do {                                                                        \
    const int T_ = t0 + (IT);                                                 \
    const char* fsrc = (const char*)fea16 + (size_t)(b * 128 + T_) * 5120;    \
    char* fdst = (char*)&lds_fea[(BUF)][0];                                   \
    gl_lds16(fsrc + wid * 1024 + lane * 16, fdst + wid * 1024);               \
    if (wid == 0) gl_lds16(fsrc + 4096 + lane * 16, fdst + 4096);             \
    if (lane < 32) {                                                          \
      const char* ysrc =                                                      \
          (const char*)ypack + ((size_t)b * 4096 + (size_t)T_ * 32) * 16;     \
      gl_lds16(ysrc + lane * 16, (char*)&lds_y[(BUF)][wid][0]);               \
    }                                                                         \
  } while (0)

  STAGE(0, 0);
  __syncthreads();

  for (int it = 0; it < NT; ++it) {
    const int buf = it & 1;
    if (it + 1 < NT) STAGE(it + 1, buf ^ 1);

    half8 a0, a1;
    const float* yb = &lds_y[buf][g][0];
#pragma unroll
    for (int j = 0; j < 8; ++j) {
      const float4 yv = *(const float4*)(yb + (g * 8 + j) * 4);
      {
        float dx = x00 - yv.x, dy = x01 - yv.y, dz = x02 - yv.z;
        float d2 = dx * dx + dy * dy + dz * dz;
        float e3 = exp2f(d2 * C3EXP);
        float e2 = e3 * e3; e2 *= e2;   // e3^4
        float e1 = e2 * e2; e1 *= e1;   // e3^16
        float kw = (W_E3 * e3 + W_E2 * e2 + W_E1 * e1) * yv.w;
        den0 += kw;
        a0[j] = (_Float16)kw;
      }
      {
        float dx = x10 - yv.x, dy = x11 - yv.y, dz = x12 - yv.z;
        float d2 = dx * dx + dy * dy + dz * dz;
        float e3 = exp2f(d2 * C3EXP);
        float e2 = e3 * e3; e2 *= e2;
        float e1 = e2 * e2; e1 *= e1;
        float kw = (W_E3 * e3 + W_E2 * e2 + W_E1 * e1) * yv.w;
        den1 += kw;
        a1[j] = (_Float16)kw;
      }
    }
    const __half* fb = &lds_fea[buf][0];
#pragma unroll
    for (int ct = 0; ct < 4; ++ct) {
      const half8 bf = *(const half8*)(fb + (ct * 16 + c0) * 40 + g * 8);
      acc[0][ct] = __builtin_amdgcn_mfma_f32_16x16x32_f16(a0, bf, acc[0][ct], 0, 0, 0);
      acc[1][ct] = __builtin_amdgcn_mfma_f32_16x16x32_f16(a1, bf, acc[1][ct], 0, 0, 0);
    }
    __syncthreads();
  }

  // reduce dens across the 4 k-groups (lanes 16 apart share the same n row)
  den0 += __shfl_xor(den0, 16);
  den0 += __shfl_xor(den0, 32);
  den1 += __shfl_xor(den1, 16);
  den1 += __shfl_xor(den1, 32);

  const size_t row0 = ((size_t)s * 2 + b) * 4096;
#pragma unroll
  for (int h = 0; h < 2; ++h) {
    const float dpart = h ? den1 : den0;
#pragma unroll
    for (int r = 0; r < 4; ++r) {
      const int n = n_base + h * 16 + g * 4 + r; // C/D row = (lane>>4)*4+reg
      const float dv = __shfl(dpart, g * 4 + r);
      if (c0 == 0) den_ws[row0 + n] = dv;
      float* nw = num_ws + (row0 + n) * 64;
#pragma unroll
      for (int ct = 0; ct < 4; ++ct) nw[ct * 16 + c0] = acc[h][ct][r];
    }
  }
}

__global__ __launch_bounds__(256) void combine_kernel(
    const float* __restrict__ num_ws, const float* __restrict__ den_ws,
    float* __restrict__ out, int S) {
  int t = blockIdx.x * 256 + threadIdx.x; // [0, B*N*C/4)
  int bn = t >> 4;
  int c4 = (t & 15) * 4;
  float sx = 0.f, sy = 0.f, sz = 0.f, sw = 0.f, d = 0.f;
  for (int s = 0; s < S; ++s) {
    const float4 v = *(const float4*)&num_ws[(((size_t)s * 8192 + bn) << 6) + c4];
    sx += v.x; sy += v.y; sz += v.z; sw += v.w;
    d += den_ws[(size_t)s * 8192 + bn];
  }
  float inv = 1.0f / (d + 1e-7f);
  float4 o; o.x = sx * inv; o.y = sy * inv; o.z = sz * inv; o.w = sw * inv;
  *(float4*)&out[((size_t)bn << 6) + c4] = o;
}

extern "C" void kernel_launch(void* const* d_in, const int* in_sizes, int n_in,
                              void* d_out, int out_size, void* d_ws, size_t ws_size,
                              hipStream_t stream) {
  const float* x = (const float*)d_in[0];
  const float* y = (const float*)d_in[1];
  const float* y_fea = (const float*)d_in[2];
  const float* y_weight = (const float*)d_in[3];
  float* out = (float*)d_out;

  char* wsb = (char*)d_ws;
  __half* fea16 = (__half*)wsb;
  float* ypack = (float*)(wsb + YPACK_OFF);
  float* num_ws = (float*)(wsb + NUM_OFF);

  int S = 8; // m-split; shrink if workspace is small
  while (S > 1 && (size_t)NUM_OFF + (size_t)S * 2129920u > ws_size) S >>= 1;
  float* den_ws = num_ws + (size_t)S * 2 * 4096 * 64;
  int NT = 128 / S; // 32-m tiles per block

  hipLaunchKernelGGL(prep_kernel, dim3(96), dim3(256), 0, stream, y, y_fea,
                     y_weight, fea16, ypack);
  hipLaunchKernelGGL(main_kernel, dim3(S, 32, 2), dim3(256), 0, stream, x,
                     fea16, ypack, num_ws, den_ws, NT);
  hipLaunchKernelGGL(combine_kernel, dim3(512), dim3(256), 0, stream, num_ws,
                     den_ws, out, S);
}

// Round 3
// 98.217 us; speedup vs baseline: 1.0091x; 1.0091x over previous
//
#include <hip/hip_runtime.h>
#include <hip/hip_fp16.h>

// ---------------------------------------------------------------------------
// MultiNadwatSpatialConv: out[b,n,c] = sum_m Kw[n,m] fea[m,c] / (sum_m Kw + eps)
//   Kw = yw*(0.3 u^16 + 0.3 u^4 + 0.4 u),  u = exp2(C3EXP*d2), d2 = |x_n-y_m|^2
//   arg = C3EXP*(x2 + y2 - 2 x.y)  (expanded, prescaled per row / per m)
// B=2, N=M=4096, C=64. f32 in/out.
// prep: fea16' = yw*fea (f16, pre-swizzled 32-m tiles), yw16, ypack(y,C3EXP*y2)
// main: per-pair score on VALU -> f16 A-frag -> MFMA num (B=fea') + den (B=yw)
// combine: sum S partials, divide.
// ---------------------------------------------------------------------------

typedef _Float16 half8 __attribute__((ext_vector_type(8)));
typedef __fp16 fp16x2 __attribute__((ext_vector_type(2)));
typedef float f32x4 __attribute__((ext_vector_type(4)));

#define C3EXP (-36.067376022224085f) /* -log2(e)/0.2^2 */

// ws layout (bytes):
//   fea16  @ 0        : B*128 tiles * (64 rows * 40 halves)   = 1,310,720
//   yw16   @ 1310720  : B*M half                               =    16,384
//   ypack  @ 1327104  : B*M float4                             =   131,072
//   num_ws @ 1458176  : S*B*N*C f32                            = S*2,097,152
//   den_ws @ after    : S*B*N f32                              = S*32,768
#define YW_OFF 1310720u
#define YPACK_OFF 1327104u
#define NUM_OFF 1458176u

__device__ __forceinline__ void gl_lds16(const void* g, void* l) {
  __builtin_amdgcn_global_load_lds(
      (const __attribute__((address_space(1))) unsigned int*)g,
      (__attribute__((address_space(3))) unsigned int*)l, 16, 0, 0);
}

__device__ __forceinline__ float kw_of(float u) {
  float t = u * u;
  float u4 = t * t;
  float q = u4 * u4;
  float u16 = q * q;
  return __builtin_fmaf(0.3f, u16, __builtin_fmaf(0.3f, u4, 0.4f * u));
}

__global__ __launch_bounds__(256) void prep_kernel(
    const float* __restrict__ y, const float* __restrict__ y_fea,
    const float* __restrict__ y_weight, __half* __restrict__ fea16,
    __half* __restrict__ yw16, float* __restrict__ ypack) {
  int t = blockIdx.x * 256 + threadIdx.x;
  if (t < 16384) {
    // one thread per (b, tile T, channel c): one 40-half padded row, yw folded
    int b = t >> 13;
    int rT = (t >> 6) & 127;
    int c = t & 63;
    alignas(16) unsigned int u[20];
    const float* src = y_fea + ((size_t)(b << 12) + (size_t)rT * 32) * 64 + c;
    const float* wsrc = y_weight + (b << 12) + rT * 32;
#pragma unroll
    for (int k = 0; k < 16; ++k) {
      float v0 = src[(2 * k) * 64] * wsrc[2 * k];
      float v1 = src[(2 * k + 1) * 64] * wsrc[2 * k + 1];
      unsigned short h0 = __half_as_ushort(__float2half(v0));
      unsigned short h1 = __half_as_ushort(__float2half(v1));
      u[k] = (unsigned int)h0 | ((unsigned int)h1 << 16);
    }
    u[16] = u[17] = u[18] = u[19] = 0u;
    uint4* dst = (uint4*)((char*)fea16 + ((size_t)((b * 128 + rT) * 64 + c)) * 80);
#pragma unroll
    for (int q = 0; q < 5; ++q) dst[q] = ((uint4*)u)[q];
  } else if (t < 16384 + 8192) {
    int t2 = t - 16384; // b*4096 + m
    float y0 = y[t2 * 3 + 0], y1 = y[t2 * 3 + 1], y2 = y[t2 * 3 + 2];
    float w = y_weight[t2];
    float4 v;
    v.x = y0; v.y = y1; v.z = y2;
    v.w = C3EXP * (y0 * y0 + y1 * y1 + y2 * y2);
    ((float4*)ypack)[t2] = v;
    yw16[t2] = __float2half(w);
  }
}

__global__ __launch_bounds__(256, 4) void main_kernel(
    const float* __restrict__ x, const __half* __restrict__ fea16,
    const __half* __restrict__ yw16, const float* __restrict__ ypack,
    float* __restrict__ num_ws, float* __restrict__ den_ws, int NT) {
  const int s = blockIdx.x;   // m-split index
  const int nb = blockIdx.y;  // n-block (128 rows each)
  const int b = blockIdx.z;   // batch
  const int tid = threadIdx.x;
  const int wid = tid >> 6, lane = tid & 63;
  const int g = lane >> 4, c0 = lane & 15;

  // fea tile: [c=64][40 halves] rows (80 B stride)
  alignas(16) __shared__ __half lds_fea[2][2560];
  alignas(16) __shared__ __half lds_yw[2][40];
  // ypack: 4 copies (one per 16-lane group) of 32 float4, 132-float stride
  alignas(16) __shared__ float lds_y[2][4][132];

  const int n_base = nb * 128 + wid * 32;
  const float* xb = x + (size_t)b * 4096 * 3;
  const int n0 = n_base + c0;
  const float a00 = xb[n0 * 3 + 0], a01 = xb[n0 * 3 + 1], a02 = xb[n0 * 3 + 2];
  const float a10 = xb[(n0 + 16) * 3 + 0], a11 = xb[(n0 + 16) * 3 + 1],
              a12 = xb[(n0 + 16) * 3 + 2];
  const float m2 = -2.0f * C3EXP;
  const float rx00 = m2 * a00, rx01 = m2 * a01, rx02 = m2 * a02;
  const float rc0 = C3EXP * (a00 * a00 + a01 * a01 + a02 * a02);
  const float rx10 = m2 * a10, rx11 = m2 * a11, rx12 = m2 * a12;
  const float rc1 = C3EXP * (a10 * a10 + a11 * a11 + a12 * a12);

  const int t0 = s * NT; // first 32-m tile for this block

  f32x4 acc[2][4], accd[2];
#pragma unroll
  for (int h = 0; h < 2; ++h) {
    accd[h] = (f32x4){0.f, 0.f, 0.f, 0.f};
#pragma unroll
    for (int ct = 0; ct < 4; ++ct) acc[h][ct] = (f32x4){0.f, 0.f, 0.f, 0.f};
  }

#define STAGE(IT, BUF)                                                        \
  do {                                                                        \
    const int T_ = t0 + (IT);                                                 \
    const char* fsrc = (const char*)fea16 + (size_t)(b * 128 + T_) * 5120;    \
    char* fdst = (char*)&lds_fea[(BUF)][0];                                   \
    gl_lds16(fsrc + wid * 1024 + lane * 16, fdst + wid * 1024);               \
    if (wid == 0) gl_lds16(fsrc + 4096 + lane * 16, fdst + 4096);             \
    if (wid == 1 && lane < 4)                                                 \
      gl_lds16((const char*)yw16 + ((size_t)b * 4096 + (size_t)T_ * 32) * 2 + \
                   lane * 16,                                                 \
               (char*)&lds_yw[(BUF)][0]);                                     \
    if (lane < 32) {                                                          \
      const char* ysrc =                                                      \
          (const char*)ypack + ((size_t)b * 4096 + (size_t)T_ * 32) * 16;     \
      gl_lds16(ysrc + lane * 16, (char*)&lds_y[(BUF)][wid][0]);               \
    }                                                                         \
  } while (0)

  STAGE(0, 0);
  __syncthreads();

  for (int it = 0; it < NT; ++it) {
    const int buf = it & 1;
    if (it + 1 < NT) STAGE(it + 1, buf ^ 1);

    half8 a0, a1;
    const float* yb = &lds_y[buf][g][0];
#pragma unroll
    for (int j = 0; j < 8; j += 2) {
      const float4 yv0 = *(const float4*)(yb + (g * 8 + j) * 4);
      const float4 yv1 = *(const float4*)(yb + (g * 8 + j + 1) * 4);
      float arg00 = __builtin_fmaf(
          rx00, yv0.x, __builtin_fmaf(rx01, yv0.y,
                                      __builtin_fmaf(rx02, yv0.z, rc0 + yv0.w)));
      float arg10 = __builtin_fmaf(
          rx10, yv0.x, __builtin_fmaf(rx11, yv0.y,
                                      __builtin_fmaf(rx12, yv0.z, rc1 + yv0.w)));
      float arg01 = __builtin_fmaf(
          rx00, yv1.x, __builtin_fmaf(rx01, yv1.y,
                                      __builtin_fmaf(rx02, yv1.z, rc0 + yv1.w)));
      float arg11 = __builtin_fmaf(
          rx10, yv1.x, __builtin_fmaf(rx11, yv1.y,
                                      __builtin_fmaf(rx12, yv1.z, rc1 + yv1.w)));
      float k00 = kw_of(__builtin_amdgcn_exp2f(arg00));
      float k01 = kw_of(__builtin_amdgcn_exp2f(arg01));
      float k10 = kw_of(__builtin_amdgcn_exp2f(arg10));
      float k11 = kw_of(__builtin_amdgcn_exp2f(arg11));
      fp16x2 p0 = __builtin_amdgcn_cvt_pkrtz(k00, k01);
      fp16x2 p1 = __builtin_amdgcn_cvt_pkrtz(k10, k11);
      a0[j] = (_Float16)p0.x; a0[j + 1] = (_Float16)p0.y;
      a1[j] = (_Float16)p1.x; a1[j + 1] = (_Float16)p1.y;
    }
    // den via MFMA: B-frag = yw[k] (col-independent)
    const half8 bw = *(const half8*)&lds_yw[buf][g * 8];
    accd[0] = __builtin_amdgcn_mfma_f32_16x16x32_f16(a0, bw, accd[0], 0, 0, 0);
    accd[1] = __builtin_amdgcn_mfma_f32_16x16x32_f16(a1, bw, accd[1], 0, 0, 0);
    const __half* fb = &lds_fea[buf][0];
#pragma unroll
    for (int ct = 0; ct < 4; ++ct) {
      const half8 bf = *(const half8*)(fb + (ct * 16 + c0) * 40 + g * 8);
      acc[0][ct] = __builtin_amdgcn_mfma_f32_16x16x32_f16(a0, bf, acc[0][ct], 0, 0, 0);
      acc[1][ct] = __builtin_amdgcn_mfma_f32_16x16x32_f16(a1, bf, acc[1][ct], 0, 0, 0);
    }
    __syncthreads();
  }

  const size_t row0 = ((size_t)s * 2 + b) * 4096;
#pragma unroll
  for (int h = 0; h < 2; ++h) {
#pragma unroll
    for (int r = 0; r < 4; ++r) {
      const int n = n_base + h * 16 + g * 4 + r; // C/D row = (lane>>4)*4+reg
      if (c0 == 0) den_ws[row0 + n] = h ? accd[1][r] : accd[0][r];
      float* nw = num_ws + (row0 + n) * 64;
#pragma unroll
      for (int ct = 0; ct < 4; ++ct) nw[ct * 16 + c0] = acc[h][ct][r];
    }
  }
}

__global__ __launch_bounds__(256) void combine_kernel(
    const float* __restrict__ num_ws, const float* __restrict__ den_ws,
    float* __restrict__ out, int S) {
  int t = blockIdx.x * 256 + threadIdx.x; // [0, B*N*C/4)
  int bn = t >> 4;
  int c4 = (t & 15) * 4;
  float sx = 0.f, sy = 0.f, sz = 0.f, sw = 0.f, d = 0.f;
  for (int s = 0; s < S; ++s) {
    const float4 v = *(const float4*)&num_ws[(((size_t)s * 8192 + bn) << 6) + c4];
    sx += v.x; sy += v.y; sz += v.z; sw += v.w;
    d += den_ws[(size_t)s * 8192 + bn];
  }
  float inv = 1.0f / (d + 1e-7f);
  float4 o; o.x = sx * inv; o.y = sy * inv; o.z = sz * inv; o.w = sw * inv;
  *(float4*)&out[((size_t)bn << 6) + c4] = o;
}

extern "C" void kernel_launch(void* const* d_in, const int* in_sizes, int n_in,
                              void* d_out, int out_size, void* d_ws, size_t ws_size,
                              hipStream_t stream) {
  const float* x = (const float*)d_in[0];
  const float* y = (const float*)d_in[1];
  const float* y_fea = (const float*)d_in[2];
  const float* y_weight = (const float*)d_in[3];
  float* out = (float*)d_out;

  char* wsb = (char*)d_ws;
  __half* fea16 = (__half*)wsb;
  __half* yw16 = (__half*)(wsb + YW_OFF);
  float* ypack = (float*)(wsb + YPACK_OFF);
  float* num_ws = (float*)(wsb + NUM_OFF);

  int S = 16; // m-split; shrink if workspace is small
  while (S > 1 && (size_t)NUM_OFF + (size_t)S * 2129920u > ws_size) S >>= 1;
  float* den_ws = num_ws + (size_t)S * 2 * 4096 * 64;
  int NT = 128 / S; // 32-m tiles per block

  hipLaunchKernelGGL(prep_kernel, dim3(96), dim3(256), 0, stream, y, y_fea,
                     y_weight, fea16, yw16, ypack);
  hipLaunchKernelGGL(main_kernel, dim3(S, 32, 2), dim3(256), 0, stream, x,
                     fea16, yw16, ypack, num_ws, den_ws, NT);
  hipLaunchKernelGGL(combine_kernel, dim3(512), dim3(256), 0, stream, num_ws,
                     den_ws, out, S);
}

// Round 10
// 96.609 us; speedup vs baseline: 1.0259x; 1.0166x over previous
//
#include <hip/hip_runtime.h>
#include <hip/hip_fp16.h>

// ---------------------------------------------------------------------------
// MultiNadwatSpatialConv: out[b,n,c] = sum_m Kw[n,m] fea[m,c] / (sum_m Kw + eps)
//   Kw = yw*(0.3 u^16 + 0.3 u^4 + 0.4 u),  u = exp2(C3EXP*d2), d2 = |x_n-y_m|^2
// B=2, N=M=4096, C=64. f32 in/out.
// R5: fused main (no partial-sum round-trip), R3-proven mechanisms only:
//  - 512 blocks x 256 thr; block owns 16 n-rows; waves split M 4-way
//    (32 private 32-m tiles per wave, double-buffered).
//  - block-wide __syncthreads() dbuf (no inline-asm waitcnt).
//  - LDS 49,920 B; epilogue reduction overlays the staging region (barriered).
// ---------------------------------------------------------------------------

typedef _Float16 half8 __attribute__((ext_vector_type(8)));
typedef __fp16 fp16x2 __attribute__((ext_vector_type(2)));
typedef float f32x4 __attribute__((ext_vector_type(4)));

#define C3EXP (-36.067376022224085f) /* -log2(e)/0.2^2 */

// ws layout (bytes):
//   fea16  @ 0        : B*128 tiles * (64 rows * 40 halves) = 1,310,720
//   yw16   @ 1310720  : B*M half                             =    16,384
//   ypack  @ 1327104  : B*M float4                           =   131,072
#define YW_OFF 1310720u
#define YPACK_OFF 1327104u

__device__ __forceinline__ void gl_lds16(const void* g, void* l) {
  __builtin_amdgcn_global_load_lds(
      (const __attribute__((address_space(1))) unsigned int*)g,
      (__attribute__((address_space(3))) unsigned int*)l, 16, 0, 0);
}

__device__ __forceinline__ float kw_of(float u) {
  float t = u * u;
  float u4 = t * t;
  float q = u4 * u4;
  float u16 = q * q;
  return __builtin_fmaf(0.3f, u16, __builtin_fmaf(0.3f, u4, 0.4f * u));
}

__global__ __launch_bounds__(256) void prep_kernel(
    const float* __restrict__ y, const float* __restrict__ y_fea,
    const float* __restrict__ y_weight, __half* __restrict__ fea16,
    __half* __restrict__ yw16, float* __restrict__ ypack) {
  int t = blockIdx.x * 256 + threadIdx.x;
  if (t < 16384) {
    // one thread per (b, tile T, channel c): one 40-half padded row, yw folded
    int b = t >> 13;
    int rT = (t >> 6) & 127;
    int c = t & 63;
    alignas(16) unsigned int u[20];
    const float* src = y_fea + ((size_t)(b << 12) + (size_t)rT * 32) * 64 + c;
    const float* wsrc = y_weight + (b << 12) + rT * 32;
#pragma unroll
    for (int k = 0; k < 16; ++k) {
      float v0 = src[(2 * k) * 64] * wsrc[2 * k];
      float v1 = src[(2 * k + 1) * 64] * wsrc[2 * k + 1];
      unsigned short h0 = __half_as_ushort(__float2half(v0));
      unsigned short h1 = __half_as_ushort(__float2half(v1));
      u[k] = (unsigned int)h0 | ((unsigned int)h1 << 16);
    }
    u[16] = u[17] = u[18] = u[19] = 0u;
    uint4* dst = (uint4*)((char*)fea16 + ((size_t)((b * 128 + rT) * 64 + c)) * 80);
#pragma unroll
    for (int q = 0; q < 5; ++q) dst[q] = ((uint4*)u)[q];
  } else if (t < 16384 + 8192) {
    int t2 = t - 16384; // b*4096 + m
    float y0 = y[t2 * 3 + 0], y1 = y[t2 * 3 + 1], y2 = y[t2 * 3 + 2];
    float w = y_weight[t2];
    float4 v;
    v.x = y0; v.y = y1; v.z = y2;
    v.w = C3EXP * (y0 * y0 + y1 * y1 + y2 * y2);
    ((float4*)ypack)[t2] = v;
    yw16[t2] = __float2half(w);
  }
}

#define NTW 32 /* 32-m tiles per wave (M=4096 / 32m / 4 waves) */

__global__ __launch_bounds__(256) void main_kernel(
    const float* __restrict__ x, const __half* __restrict__ fea16,
    const __half* __restrict__ yw16, const float* __restrict__ ypack,
    float* __restrict__ out) {
  const int blk = blockIdx.x;       // [0, 512)
  const int b = blk >> 8;           // batch
  const int n0 = (blk & 255) * 16;  // 16 n-rows per block
  const int tid = threadIdx.x;
  const int wid = tid >> 6, lane = tid & 63;
  const int g = lane >> 4, c0 = lane & 15;

  // one shared pool; staging region overlaid by epilogue reduction scratch
  //   staging: fea [4][2][2560]h @0 (40,960) | y [4][2][2][132]f @40,960
  //            (8,448) | yw [4][2][32]h @49,408 (512)   -> 49,920 B total
  //   epilogue overlay: red [4][16][64]f @0 (16,384) | den [4][16]f @16,384
  alignas(16) __shared__ char smem[49920];
  __half* lds_fea = (__half*)smem;
  float* lds_y = (float*)(smem + 40960);
  __half* lds_yw = (__half*)(smem + 49408);
  float* lds_red = (float*)smem;
  float* lds_den = (float*)(smem + 16384);

  const float* xb = x + (size_t)b * 4096 * 3;
  const int n = n0 + c0;
  const float a0x = xb[n * 3 + 0], a0y = xb[n * 3 + 1], a0z = xb[n * 3 + 2];
  const float m2 = -2.0f * C3EXP;
  const float rx0 = m2 * a0x, rx1 = m2 * a0y, rx2 = m2 * a0z;
  const float rc = C3EXP * (a0x * a0x + a0y * a0y + a0z * a0z);

  const int wtile0 = wid * NTW;

  f32x4 acc[4], accd;
  accd = (f32x4){0.f, 0.f, 0.f, 0.f};
#pragma unroll
  for (int ct = 0; ct < 4; ++ct) acc[ct] = (f32x4){0.f, 0.f, 0.f, 0.f};

#define STAGE(IT, BUF)                                                         \
  do {                                                                         \
    const int T_ = wtile0 + (IT);                                              \
    const char* fsrc = (const char*)fea16 + (size_t)(b * 128 + T_) * 5120;     \
    char* fdst = (char*)lds_fea + (wid * 2 + (BUF)) * 5120;                    \
    gl_lds16(fsrc + lane * 16, fdst);                                          \
    gl_lds16(fsrc + 1024 + lane * 16, fdst + 1024);                            \
    gl_lds16(fsrc + 2048 + lane * 16, fdst + 2048);                            \
    gl_lds16(fsrc + 3072 + lane * 16, fdst + 3072);                            \
    gl_lds16(fsrc + 4096 + lane * 16, fdst + 4096);                            \
    const char* ysrc =                                                         \
        (const char*)ypack + ((size_t)b * 4096 + (size_t)T_ * 32) * 16;        \
    char* ydst = (char*)lds_y + (wid * 2 + (BUF)) * 1056;                      \
    if (lane < 32) {                                                           \
      gl_lds16(ysrc + lane * 16, ydst);                                        \
      gl_lds16(ysrc + lane * 16, ydst + 528);                                  \
    }                                                                          \
    if (lane < 4)                                                              \
      gl_lds16((const char*)yw16 + ((size_t)b * 4096 + (size_t)T_ * 32) * 2 +  \
                   lane * 16,                                                  \
               (char*)lds_yw + (wid * 2 + (BUF)) * 64);                        \
  } while (0)

  STAGE(0, 0);
  __syncthreads();

  for (int it = 0; it < NTW; ++it) {
    const int buf = it & 1;
    if (it + 1 < NTW) STAGE(it + 1, buf ^ 1);

    half8 a;
    const float* yb =
        (const float*)((char*)lds_y + (wid * 2 + buf) * 1056 + (g >> 1) * 528);
#pragma unroll
    for (int j = 0; j < 8; j += 2) {
      const float4 yv0 = *(const float4*)(yb + (g * 8 + j) * 4);
      const float4 yv1 = *(const float4*)(yb + (g * 8 + j + 1) * 4);
      float arg0 = __builtin_fmaf(
          rx0, yv0.x,
          __builtin_fmaf(rx1, yv0.y, __builtin_fmaf(rx2, yv0.z, rc + yv0.w)));
      float arg1 = __builtin_fmaf(
          rx0, yv1.x,
          __builtin_fmaf(rx1, yv1.y, __builtin_fmaf(rx2, yv1.z, rc + yv1.w)));
      float k0 = kw_of(__builtin_amdgcn_exp2f(arg0));
      float k1 = kw_of(__builtin_amdgcn_exp2f(arg1));
      fp16x2 p = __builtin_amdgcn_cvt_pkrtz(k0, k1);
      a[j] = (_Float16)p.x;
      a[j + 1] = (_Float16)p.y;
    }
    // den via MFMA: B-frag = yw[k] (col-independent)
    const half8 bw =
        *(const half8*)((char*)lds_yw + (wid * 2 + buf) * 64 + g * 16);
    accd = __builtin_amdgcn_mfma_f32_16x16x32_f16(a, bw, accd, 0, 0, 0);
    const __half* fb = (const __half*)((char*)lds_fea + (wid * 2 + buf) * 5120);
#pragma unroll
    for (int ct = 0; ct < 4; ++ct) {
      const half8 bf = *(const half8*)(fb + (ct * 16 + c0) * 40 + g * 8);
      acc[ct] = __builtin_amdgcn_mfma_f32_16x16x32_f16(a, bf, acc[ct], 0, 0, 0);
    }
    __syncthreads();
  }

  // epilogue: all waves past the final barrier -> staging LDS reusable.
  // C/D layout: row=(lane>>4)*4+reg, col=lane&15
#pragma unroll
  for (int ct = 0; ct < 4; ++ct)
#pragma unroll
    for (int r = 0; r < 4; ++r)
      lds_red[(wid * 16 + g * 4 + r) * 64 + ct * 16 + c0] = acc[ct][r];
  if (c0 == 0) {
#pragma unroll
    for (int r = 0; r < 4; ++r) lds_den[wid * 16 + g * 4 + r] = accd[r];
  }
  __syncthreads();

  // cross-wave sum + normalize + store: thread t -> (row, 4-channel chunk)
  {
    const int row = tid >> 4;
    const int c4 = (tid & 15) * 4;
    float4 s = {0.f, 0.f, 0.f, 0.f};
    float d = 0.f;
#pragma unroll
    for (int w = 0; w < 4; ++w) {
      const float4 v = *(const float4*)&lds_red[(w * 16 + row) * 64 + c4];
      s.x += v.x; s.y += v.y; s.z += v.z; s.w += v.w;
      d += lds_den[w * 16 + row];
    }
    const float inv = 1.0f / (d + 1e-7f);
    float4 o;
    o.x = s.x * inv; o.y = s.y * inv; o.z = s.z * inv; o.w = s.w * inv;
    *(float4*)&out[((size_t)(b * 4096 + n0 + row)) * 64 + c4] = o;
  }
}

extern "C" void kernel_launch(void* const* d_in, const int* in_sizes, int n_in,
                              void* d_out, int out_size, void* d_ws, size_t ws_size,
                              hipStream_t stream) {
  const float* x = (const float*)d_in[0];
  const float* y = (const float*)d_in[1];
  const float* y_fea = (const float*)d_in[2];
  const float* y_weight = (const float*)d_in[3];
  float* out = (float*)d_out;

  char* wsb = (char*)d_ws;
  __half* fea16 = (__half*)wsb;
  __half* yw16 = (__half*)(wsb + YW_OFF);
  float* ypack = (float*)(wsb + YPACK_OFF);

  hipLaunchKernelGGL(prep_kernel, dim3(96), dim3(256), 0, stream, y, y_fea,
                     y_weight, fea16, yw16, ypack);
  hipLaunchKernelGGL(main_kernel, dim3(512), dim3(256), 0, stream, x, fea16,
                     yw16, ypack, out);
}

// Round 14
// 93.267 us; speedup vs baseline: 1.0627x; 1.0358x over previous
//
#include <hip/hip_runtime.h>
#include <hip/hip_fp16.h>

// ---------------------------------------------------------------------------
// MultiNadwatSpatialConv: out[b,n,c] = sum_m Kw[n,m] fea[m,c] / (sum_m Kw + eps)
//   Kw = yw*(0.3 u^16 + 0.3 u^4 + 0.4 u),  u = exp2(C3EXP*d2), d2 = |x_n-y_m|^2
// B=2, N=M=4096, C=64. f32 in/out.
// R11 = R10 + no-barrier hot loop: per-wave private dbuf staging ordered by
// counted s_waitcnt vmcnt(8) (T4) + sched_barrier(0); __syncthreads only in
// the epilogue (LDS overlay needs cross-wave ordering). LDS 49,920 B < 64 KB
// (R4's abort was the 66,560 B static-LDS limit violation, not the pipeline).
// ---------------------------------------------------------------------------

typedef _Float16 half8 __attribute__((ext_vector_type(8)));
typedef __fp16 fp16x2 __attribute__((ext_vector_type(2)));
typedef float f32x4 __attribute__((ext_vector_type(4)));

#define C3EXP (-36.067376022224085f) /* -log2(e)/0.2^2 */

// ws layout (bytes):
//   fea16  @ 0        : B*128 tiles * (64 rows * 40 halves) = 1,310,720
//   yw16   @ 1310720  : B*M half                             =    16,384
//   ypack  @ 1327104  : B*M float4                           =   131,072
#define YW_OFF 1310720u
#define YPACK_OFF 1327104u

__device__ __forceinline__ void gl_lds16(const void* g, void* l) {
  __builtin_amdgcn_global_load_lds(
      (const __attribute__((address_space(1))) unsigned int*)g,
      (__attribute__((address_space(3))) unsigned int*)l, 16, 0, 0);
}

__device__ __forceinline__ float kw_of(float u) {
  float t = u * u;
  float u4 = t * t;
  float q = u4 * u4;
  float u16 = q * q;
  return __builtin_fmaf(0.3f, u16, __builtin_fmaf(0.3f, u4, 0.4f * u));
}

__global__ __launch_bounds__(256) void prep_kernel(
    const float* __restrict__ y, const float* __restrict__ y_fea,
    const float* __restrict__ y_weight, __half* __restrict__ fea16,
    __half* __restrict__ yw16, float* __restrict__ ypack) {
  int t = blockIdx.x * 256 + threadIdx.x;
  if (t < 16384) {
    // one thread per (b, tile T, channel c): one 40-half padded row, yw folded
    int b = t >> 13;
    int rT = (t >> 6) & 127;
    int c = t & 63;
    alignas(16) unsigned int u[20];
    const float* src = y_fea + ((size_t)(b << 12) + (size_t)rT * 32) * 64 + c;
    const float* wsrc = y_weight + (b << 12) + rT * 32;
#pragma unroll
    for (int k = 0; k < 16; ++k) {
      float v0 = src[(2 * k) * 64] * wsrc[2 * k];
      float v1 = src[(2 * k + 1) * 64] * wsrc[2 * k + 1];
      unsigned short h0 = __half_as_ushort(__float2half(v0));
      unsigned short h1 = __half_as_ushort(__float2half(v1));
      u[k] = (unsigned int)h0 | ((unsigned int)h1 << 16);
    }
    u[16] = u[17] = u[18] = u[19] = 0u;
    uint4* dst = (uint4*)((char*)fea16 + ((size_t)((b * 128 + rT) * 64 + c)) * 80);
#pragma unroll
    for (int q = 0; q < 5; ++q) dst[q] = ((uint4*)u)[q];
  } else if (t < 16384 + 8192) {
    int t2 = t - 16384; // b*4096 + m
    float y0 = y[t2 * 3 + 0], y1 = y[t2 * 3 + 1], y2 = y[t2 * 3 + 2];
    float w = y_weight[t2];
    float4 v;
    v.x = y0; v.y = y1; v.z = y2;
    v.w = C3EXP * (y0 * y0 + y1 * y1 + y2 * y2);
    ((float4*)ypack)[t2] = v;
    yw16[t2] = __float2half(w);
  }
}

#define NTW 32 /* 32-m tiles per wave (M=4096 / 32m / 4 waves) */

__global__ __launch_bounds__(256) void main_kernel(
    const float* __restrict__ x, const __half* __restrict__ fea16,
    const __half* __restrict__ yw16, const float* __restrict__ ypack,
    float* __restrict__ out) {
  const int blk = blockIdx.x;       // [0, 512)
  const int b = blk >> 8;           // batch
  const int n0 = (blk & 255) * 16;  // 16 n-rows per block
  const int tid = threadIdx.x;
  const int wid = tid >> 6, lane = tid & 63;
  const int g = lane >> 4, c0 = lane & 15;

  // one shared pool; staging region overlaid by epilogue reduction scratch
  //   staging: fea [4][2][2560]h @0 (40,960) | y [4][2][2][132]f @40,960
  //            (8,448) | yw [4][2][32]h @49,408 (512)   -> 49,920 B total
  //   epilogue overlay: red [4][16][64]f @0 (16,384) | den [4][16]f @16,384
  alignas(16) __shared__ char smem[49920];
  __half* lds_fea = (__half*)smem;
  float* lds_y = (float*)(smem + 40960);
  __half* lds_yw = (__half*)(smem + 49408);
  float* lds_red = (float*)smem;
  float* lds_den = (float*)(smem + 16384);

  const float* xb = x + (size_t)b * 4096 * 3;
  const int n = n0 + c0;
  const float a0x = xb[n * 3 + 0], a0y = xb[n * 3 + 1], a0z = xb[n * 3 + 2];
  const float m2 = -2.0f * C3EXP;
  const float rx0 = m2 * a0x, rx1 = m2 * a0y, rx2 = m2 * a0z;
  const float rc = C3EXP * (a0x * a0x + a0y * a0y + a0z * a0z);

  const int wtile0 = wid * NTW;

  f32x4 acc[4], accd;
  accd = (f32x4){0.f, 0.f, 0.f, 0.f};
#pragma unroll
  for (int ct = 0; ct < 4; ++ct) acc[ct] = (f32x4){0.f, 0.f, 0.f, 0.f};

#define STAGE(IT, BUF)                                                         \
  do {                                                                         \
    const int T_ = wtile0 + (IT);                                              \
    const char* fsrc = (const char*)fea16 + (size_t)(b * 128 + T_) * 5120;     \
    char* fdst = (char*)lds_fea + (wid * 2 + (BUF)) * 5120;                    \
    gl_lds16(fsrc + lane * 16, fdst);                                          \
    gl_lds16(fsrc + 1024 + lane * 16, fdst + 1024);                            \
    gl_lds16(fsrc + 2048 + lane * 16, fdst + 2048);                            \
    gl_lds16(fsrc + 3072 + lane * 16, fdst + 3072);                            \
    gl_lds16(fsrc + 4096 + lane * 16, fdst + 4096);                            \
    const char* ysrc =                                                         \
        (const char*)ypack + ((size_t)b * 4096 + (size_t)T_ * 32) * 16;        \
    char* ydst = (char*)lds_y + (wid * 2 + (BUF)) * 1056;                      \
    if (lane < 32) {                                                           \
      gl_lds16(ysrc + lane * 16, ydst);                                        \
      gl_lds16(ysrc + lane * 16, ydst + 528);                                  \
    }                                                                          \
    if (lane < 4)                                                              \
      gl_lds16((const char*)yw16 + ((size_t)b * 4096 + (size_t)T_ * 32) * 2 +  \
                   lane * 16,                                                  \
               (char*)lds_yw + (wid * 2 + (BUF)) * 64);                        \
  } while (0)

  STAGE(0, 0);

  for (int it = 0; it < NTW; ++it) {
    const int buf = it & 1;
    // per-wave pipeline: issue next tile, then wait ONLY for current tile
    // (8 loads per STAGE -> counted vmcnt(8) keeps next tile in flight).
    if (it + 1 < NTW) {
      STAGE(it + 1, buf ^ 1);
      asm volatile("s_waitcnt vmcnt(8)" ::: "memory");
    } else {
      asm volatile("s_waitcnt vmcnt(0)" ::: "memory");
    }
    __builtin_amdgcn_sched_barrier(0);

    half8 a;
    const float* yb =
        (const float*)((char*)lds_y + (wid * 2 + buf) * 1056 + (g >> 1) * 528);
#pragma unroll
    for (int j = 0; j < 8; j += 2) {
      const float4 yv0 = *(const float4*)(yb + (g * 8 + j) * 4);
      const float4 yv1 = *(const float4*)(yb + (g * 8 + j + 1) * 4);
      float arg0 = __builtin_fmaf(
          rx0, yv0.x,
          __builtin_fmaf(rx1, yv0.y, __builtin_fmaf(rx2, yv0.z, rc + yv0.w)));
      float arg1 = __builtin_fmaf(
          rx0, yv1.x,
          __builtin_fmaf(rx1, yv1.y, __builtin_fmaf(rx2, yv1.z, rc + yv1.w)));
      float k0 = kw_of(__builtin_amdgcn_exp2f(arg0));
      float k1 = kw_of(__builtin_amdgcn_exp2f(arg1));
      fp16x2 p = __builtin_amdgcn_cvt_pkrtz(k0, k1);
      a[j] = (_Float16)p.x;
      a[j + 1] = (_Float16)p.y;
    }
    // den via MFMA: B-frag = yw[k] (col-independent)
    const half8 bw =
        *(const half8*)((char*)lds_yw + (wid * 2 + buf) * 64 + g * 16);
    accd = __builtin_amdgcn_mfma_f32_16x16x32_f16(a, bw, accd, 0, 0, 0);
    const __half* fb = (const __half*)((char*)lds_fea + (wid * 2 + buf) * 5120);
#pragma unroll
    for (int ct = 0; ct < 4; ++ct) {
      const half8 bf = *(const half8*)(fb + (ct * 16 + c0) * 40 + g * 8);
      acc[ct] = __builtin_amdgcn_mfma_f32_16x16x32_f16(a, bf, acc[ct], 0, 0, 0);
    }
    // lgkmcnt for the ds_reads is enforced by the compiler before the MFMAs;
    // next STAGE's LDS writes land >=1 full compute phase later, after the
    // epilogue-ordered __syncthreads there is no cross-wave hazard.
  }

  // epilogue: cross-wave ordering required before overlaying staging LDS.
  __syncthreads();
  // C/D layout: row=(lane>>4)*4+reg, col=lane&15
#pragma unroll
  for (int ct = 0; ct < 4; ++ct)
#pragma unroll
    for (int r = 0; r < 4; ++r)
      lds_red[(wid * 16 + g * 4 + r) * 64 + ct * 16 + c0] = acc[ct][r];
  if (c0 == 0) {
#pragma unroll
    for (int r = 0; r < 4; ++r) lds_den[wid * 16 + g * 4 + r] = accd[r];
  }
  __syncthreads();

  // cross-wave sum + normalize + store: thread t -> (row, 4-channel chunk)
  {
    const int row = tid >> 4;
    const int c4 = (tid & 15) * 4;
    float4 s = {0.f, 0.f, 0.f, 0.f};
    float d = 0.f;
#pragma unroll
    for (int w = 0; w < 4; ++w) {
      const float4 v = *(const float4*)&lds_red[(w * 16 + row) * 64 + c4];
      s.x += v.x; s.y += v.y; s.z += v.z; s.w += v.w;
      d += lds_den[w * 16 + row];
    }
    const float inv = 1.0f / (d + 1e-7f);
    float4 o;
    o.x = s.x * inv; o.y = s.y * inv; o.z = s.z * inv; o.w = s.w * inv;
    *(float4*)&out[((size_t)(b * 4096 + n0 + row)) * 64 + c4] = o;
  }
}

extern "C" void kernel_launch(void* const* d_in, const int* in_sizes, int n_in,
                              void* d_out, int out_size, void* d_ws, size_t ws_size,
                              hipStream_t stream) {
  const float* x = (const float*)d_in[0];
  const float* y = (const float*)d_in[1];
  const float* y_fea = (const float*)d_in[2];
  const float* y_weight = (const float*)d_in[3];
  float* out = (float*)d_out;

  char* wsb = (char*)d_ws;
  __half* fea16 = (__half*)wsb;
  __half* yw16 = (__half*)(wsb + YW_OFF);
  float* ypack = (float*)(wsb + YPACK_OFF);

  hipLaunchKernelGGL(prep_kernel, dim3(96), dim3(256), 0, stream, y, y_fea,
                     y_weight, fea16, yw16, ypack);
  hipLaunchKernelGGL(main_kernel, dim3(512), dim3(256), 0, stream, x, fea16,
                     yw16, ypack, out);
}